// Round 11
// baseline (1336.284 us; speedup 1.0000x reference)
//
#include <hip/hip_runtime.h>
#include <hip/hip_bf16.h>

namespace {

typedef _Float16 h16;
typedef _Float16 f16x8 __attribute__((ext_vector_type(8)));
typedef _Float16 f16x4 __attribute__((ext_vector_type(4)));
typedef float    f32x4 __attribute__((ext_vector_type(4)));

constexpr int T_SEQ = 512;
constexpr int B_SZ  = 1024;
constexpr int H_DIM = 128;
constexpr int ROWS  = 16;    // batch rows per block (MFMA N-tile)
constexpr int NT    = 512;   // 8 waves, 2/SIMD
constexpr int CH    = 4;     // K-chunks over a 128-dim operand
constexpr int CX    = 2;     // K-chunks over x (64)

// Frag-major LDS (r10, conflict-verified: 17.8M -> 2.1M): slot = one f16x8
// (16B) = one lane's chunk. Reads are lane-linear 1KB contiguous.
constexpr int FH1 = 0;                 // h1-state frags [2][CH][64]
constexpr int FX  = 2 * CH * 64;       // x frags        [2][CX][64]
constexpr int FH2 = FX + 2 * CX * 64;  // h2-state frags [2][CH][64]
constexpr int NSLOT = FH2 + 2 * CH * 64;  // 1280 slots = 20 KB

// Fused 2-layer GRU, one block per 16 batch rows, 513 step-slots.
// Step g (one region, max ILP):
//   bh  = h1(g-1) frags   -> l0 recurrence chains (aR,aZ,aNh) AND l1-input
//                            chains (xR,xZ,xN) — xg1 never touches LDS
//   bx  = x(g) frags      -> l0 input chains
//   bh2 = h2(g-2) frags   -> l1 recurrence chains (rR,rZ,rNh), zero-init,
//                            INDEPENDENT of xg (r10's serialization bug);
//                            merged at gate time by 3 f32x4 adds.
// Frag convention verified on HW (rounds 4-10, absmax 1.2e-4):
//  A row = lane&15 (gate in tile), k = (lane>>4)*8 + e + 32*ks
//  B col = lane&15 (batch), same k;  D: col = lane&15, row = (lane>>4)*4 + i
__global__ __launch_bounds__(NT, 1)
void gru2(const float* __restrict__ x,      // [B][T][64] f32
          const float* __restrict__ w_ih0,  // [384][64]
          const float* __restrict__ w_hh0,  // [384][128]
          const float* __restrict__ b_ih0, const float* __restrict__ b_hh0,
          const float* __restrict__ w_ih1,  // [384][128]
          const float* __restrict__ w_hh1,  // [384][128]
          const float* __restrict__ b_ih1, const float* __restrict__ b_hh1,
          float* __restrict__ h2out)        // [B][128]
{
  __shared__ __align__(16) h16 lds[NSLOT * 8];

  const int tid = threadIdx.x;
  const int wv  = tid >> 6;        // wave 0..7
  const int ln  = tid & 63;
  const int q   = ln >> 4;
  const int lr  = ln & 15;
  const int r0  = blockIdx.x * ROWS;
  const int j0  = wv * 16 + q * 4;

  // gate-update write slot (frag-major element of (batch=lr, gates j0..j0+3))
  const int slotH = (wv >> 1) * 64 + ((wv & 1) * 2 + (q >> 1)) * 16 + lr;
  const int e0    = (q & 1) * 4;

  auto ldw = [](const float* pw) {
    const float4 v0 = *(const float4*)(pw);
    const float4 v1 = *(const float4*)(pw + 4);
    f16x8 f;
    f[0]=(h16)v0.x; f[1]=(h16)v0.y; f[2]=(h16)v0.z; f[3]=(h16)v0.w;
    f[4]=(h16)v1.x; f[5]=(h16)v1.y; f[6]=(h16)v1.z; f[7]=(h16)v1.w;
    return f;
  };

  // ---- weights -> fp16 MFMA A-frags ----
  f16x8 wA0[3][CH], wB0[3][CX], wI1[3][CH], wA1[3][CH];
  #pragma unroll
  for (int p = 0; p < 3; ++p) {
    const int g = p * H_DIM + wv * 16 + lr;
    #pragma unroll
    for (int ks = 0; ks < CH; ++ks) {
      wA0[p][ks] = ldw(w_hh0 + (size_t)g * H_DIM + ks * 32 + q * 8);
      wI1[p][ks] = ldw(w_ih1 + (size_t)g * H_DIM + ks * 32 + q * 8);
      wA1[p][ks] = ldw(w_hh1 + (size_t)g * H_DIM + ks * 32 + q * 8);
    }
    #pragma unroll
    for (int ks = 0; ks < CX; ++ks)
      wB0[p][ks] = ldw(w_ih0 + (size_t)g * 64 + ks * 32 + q * 8);
  }

  // ---- biases folded into MFMA C-init ----
  f32x4 bR0, bZ0, bNx0, bNh0, bR1, bZ1, bNx1, bNh1;
  {
    auto mkb = [&](const float* bi, const float* bh,
                   f32x4& bR, f32x4& bZ, f32x4& bNx, f32x4& bNh) {
      const float4 ir  = *(const float4*)&bi[j0];
      const float4 hr  = *(const float4*)&bh[j0];
      const float4 iz  = *(const float4*)&bi[H_DIM + j0];
      const float4 hz  = *(const float4*)&bh[H_DIM + j0];
      const float4 in_ = *(const float4*)&bi[2 * H_DIM + j0];
      const float4 hn  = *(const float4*)&bh[2 * H_DIM + j0];
      bR[0]=ir.x+hr.x; bR[1]=ir.y+hr.y; bR[2]=ir.z+hr.z; bR[3]=ir.w+hr.w;
      bZ[0]=iz.x+hz.x; bZ[1]=iz.y+hz.y; bZ[2]=iz.z+hz.z; bZ[3]=iz.w+hz.w;
      bNx[0]=in_.x; bNx[1]=in_.y; bNx[2]=in_.z; bNx[3]=in_.w;
      bNh[0]=hn.x;  bNh[1]=hn.y;  bNh[2]=hn.z;  bNh[3]=hn.w;
    };
    mkb(b_ih0, b_hh0, bR0, bZ0, bNx0, bNh0);
    mkb(b_ih1, b_hh1, bR1, bZ1, bNx1, bNh1);
  }

  // ---- x staging: thread tid<128 owns frag (chunk sc, lane sl) ----
  const int  sc  = tid >> 6;
  const int  sl  = tid & 63;
  const bool stg = (tid < CX * 64);
  const size_t xrow = (size_t)(r0 + (sl & 15)) * T_SEQ;
  const int    xk   = (sl >> 4) * 8 + sc * 32;

  auto load_x = [&](int t, f16x8& d) {
    if (stg) {
      const float* p = x + (xrow + t) * 64 + xk;
      const float4 v0 = *(const float4*)(p);
      const float4 v1 = *(const float4*)(p + 4);
      d[0]=(h16)v0.x; d[1]=(h16)v0.y; d[2]=(h16)v0.z; d[3]=(h16)v0.w;
      d[4]=(h16)v1.x; d[5]=(h16)v1.y; d[6]=(h16)v1.z; d[7]=(h16)v1.w;
    }
  };
  auto stage_x = [&](int buf, const f16x8& s) {
    if (stg) *(f16x8*)&lds[(FX + buf * CX * 64 + sc * 64 + sl) * 8] = s;
  };
  auto rd = [&](int cb) { return *(const f16x8*)&lds[(cb + ln) * 8]; };

  // ---- prologue: zero h1(-1) frags (buf0) and h2(-1) frags (buf1) ----
  {
    f16x8 z; z[0]=z[1]=z[2]=z[3]=z[4]=z[5]=z[6]=z[7] = (h16)0.f;
    if (tid < 256) *(f16x8*)&lds[(FH1 + tid) * 8] = z;
    else           *(f16x8*)&lds[(FH2 + 256 + (tid - 256)) * 8] = z;
  }
  f16x8 s0; load_x(0, s0); stage_x(0, s0);
  f16x8 sA; load_x(1, sA);
  f16x8 sB;
  f16x4 h_old0, h_old1;
  h_old0[0]=h_old0[1]=h_old0[2]=h_old0[3] = (h16)0.f;
  h_old1 = h_old0;
  __syncthreads();

  auto gates = [&](const f32x4& aR, const f32x4& aZ, const f32x4& aNx,
                   const f32x4& aNh, f16x4& h_old, float* hnv) -> f16x4 {
    f16x4 nv4;
    #pragma unroll
    for (int i = 0; i < 4; ++i) {
      const float rg = __builtin_amdgcn_rcpf(1.f + __expf(-aR[i]));
      const float zg = __builtin_amdgcn_rcpf(1.f + __expf(-aZ[i]));
      const float na = aNx[i] + rg * aNh[i];
      const float e2 = __expf(2.f * na);
      const float ng = 1.f - 2.f * __builtin_amdgcn_rcpf(e2 + 1.f);
      const float ho = (float)h_old[i];
      const float hn = ng + zg * (ho - ng);
      hnv[i] = hn;
      nv4[i] = (h16)hn;
    }
    h_old = nv4;
    return nv4;
  };

  // ---- full fused step g (cur = g&1): one region, 9 independent chains ----
  auto step_full = [&](int g, int cur, f16x8& s_use, f16x8& s_load) {
    f16x8 bh[CH], bx[CX], bh2[CH];
    #pragma unroll
    for (int ks = 0; ks < CH; ++ks) bh[ks]  = rd(FH1 + cur * 256 + ks * 64);
    #pragma unroll
    for (int c = 0; c < CX; ++c)    bx[c]   = rd(FX + cur * CX * 64 + c * 64);
    #pragma unroll
    for (int ks = 0; ks < CH; ++ks) bh2[ks] = rd(FH2 + cur * 256 + ks * 64);

    load_x((g + 2 < T_SEQ) ? g + 2 : T_SEQ - 1, s_load);

    f32x4 aR = bR0, aZ = bZ0, aNh = bNh0, aNx = bNx0;  // l0
    f32x4 xR = bR1, xZ = bZ1, xN = bNx1;               // l1 input (on bh)
    f32x4 rR = (f32x4)(0.f), rZ = (f32x4)(0.f), rNh = bNh1;  // l1 recurrence

    // bh-consumers first (partial lgkmcnt), bh2-consumers last
    #pragma unroll
    for (int ks = 0; ks < CH; ++ks) {
      aR  = __builtin_amdgcn_mfma_f32_16x16x32_f16(wA0[0][ks], bh[ks],  aR,  0, 0, 0);
      xR  = __builtin_amdgcn_mfma_f32_16x16x32_f16(wI1[0][ks], bh[ks],  xR,  0, 0, 0);
      aZ  = __builtin_amdgcn_mfma_f32_16x16x32_f16(wA0[1][ks], bh[ks],  aZ,  0, 0, 0);
      xZ  = __builtin_amdgcn_mfma_f32_16x16x32_f16(wI1[1][ks], bh[ks],  xZ,  0, 0, 0);
      aNh = __builtin_amdgcn_mfma_f32_16x16x32_f16(wA0[2][ks], bh[ks],  aNh, 0, 0, 0);
      xN  = __builtin_amdgcn_mfma_f32_16x16x32_f16(wI1[2][ks], bh[ks],  xN,  0, 0, 0);
      rR  = __builtin_amdgcn_mfma_f32_16x16x32_f16(wA1[0][ks], bh2[ks], rR,  0, 0, 0);
      rZ  = __builtin_amdgcn_mfma_f32_16x16x32_f16(wA1[1][ks], bh2[ks], rZ,  0, 0, 0);
      rNh = __builtin_amdgcn_mfma_f32_16x16x32_f16(wA1[2][ks], bh2[ks], rNh, 0, 0, 0);
    }
    #pragma unroll
    for (int c = 0; c < CX; ++c) {
      aR  = __builtin_amdgcn_mfma_f32_16x16x32_f16(wB0[0][c], bx[c], aR,  0, 0, 0);
      aZ  = __builtin_amdgcn_mfma_f32_16x16x32_f16(wB0[1][c], bx[c], aZ,  0, 0, 0);
      aNx = __builtin_amdgcn_mfma_f32_16x16x32_f16(wB0[2][c], bx[c], aNx, 0, 0, 0);
    }

    // l0 gates -> h1(g)
    float hnv0[4];
    const f16x4 nv0 = gates(aR, aZ, aNx, aNh, h_old0, hnv0);
    *(f16x4*)&lds[(FH1 + (cur ^ 1) * 256 + slotH) * 8 + e0] = nv0;
    stage_x(cur ^ 1, s_use);

    // l1 gates -> h2(g-1): merge xg + recurrence (3 cheap adds)
    f32x4 tR, tZ;
    #pragma unroll
    for (int i = 0; i < 4; ++i) { tR[i] = xR[i] + rR[i]; tZ[i] = xZ[i] + rZ[i]; }
    float hnv1[4];
    const f16x4 nv1 = gates(tR, tZ, xN, rNh, h_old1, hnv1);
    *(f16x4*)&lds[(FH2 + (cur ^ 1) * 256 + slotH) * 8 + e0] = nv1;

    __syncthreads();
  };

  // ---- g = 0: l0 only ----
  {
    f16x8 bh[CH], bx[CX];
    #pragma unroll
    for (int ks = 0; ks < CH; ++ks) bh[ks] = rd(FH1 + ks * 64);
    #pragma unroll
    for (int c = 0; c < CX; ++c)    bx[c]  = rd(FX + c * 64);
    load_x(2, sB);

    f32x4 aR = bR0, aZ = bZ0, aNh = bNh0, aNx = bNx0;
    #pragma unroll
    for (int ks = 0; ks < CH; ++ks) {
      aR  = __builtin_amdgcn_mfma_f32_16x16x32_f16(wA0[0][ks], bh[ks], aR,  0, 0, 0);
      aZ  = __builtin_amdgcn_mfma_f32_16x16x32_f16(wA0[1][ks], bh[ks], aZ,  0, 0, 0);
      aNh = __builtin_amdgcn_mfma_f32_16x16x32_f16(wA0[2][ks], bh[ks], aNh, 0, 0, 0);
    }
    #pragma unroll
    for (int c = 0; c < CX; ++c) {
      aR  = __builtin_amdgcn_mfma_f32_16x16x32_f16(wB0[0][c], bx[c], aR,  0, 0, 0);
      aZ  = __builtin_amdgcn_mfma_f32_16x16x32_f16(wB0[1][c], bx[c], aZ,  0, 0, 0);
      aNx = __builtin_amdgcn_mfma_f32_16x16x32_f16(wB0[2][c], bx[c], aNx, 0, 0, 0);
    }
    float hnv0[4];
    const f16x4 nv0 = gates(aR, aZ, aNx, aNh, h_old0, hnv0);
    *(f16x4*)&lds[(FH1 + 256 + slotH) * 8 + e0] = nv0;
    stage_x(1, sA);
    __syncthreads();
  }

  // ---- g = 1..510 ----
  #pragma unroll 1
  for (int k = 0; k <= 254; ++k) {
    step_full(2 * k + 1, 1, sB, sA);
    step_full(2 * k + 2, 0, sA, sB);
  }
  // ---- g = 511 ----
  step_full(511, 1, sB, sA);

  // ---- g = 512: l1 only; h2(511) -> out ----
  {
    f16x8 bh[CH], bh2[CH];
    #pragma unroll
    for (int ks = 0; ks < CH; ++ks) bh[ks]  = rd(FH1 + ks * 64);
    #pragma unroll
    for (int ks = 0; ks < CH; ++ks) bh2[ks] = rd(FH2 + ks * 64);

    f32x4 xR = bR1, xZ = bZ1, xN = bNx1;
    f32x4 rR = (f32x4)(0.f), rZ = (f32x4)(0.f), rNh = bNh1;
    #pragma unroll
    for (int ks = 0; ks < CH; ++ks) {
      xR  = __builtin_amdgcn_mfma_f32_16x16x32_f16(wI1[0][ks], bh[ks],  xR,  0, 0, 0);
      xZ  = __builtin_amdgcn_mfma_f32_16x16x32_f16(wI1[1][ks], bh[ks],  xZ,  0, 0, 0);
      xN  = __builtin_amdgcn_mfma_f32_16x16x32_f16(wI1[2][ks], bh[ks],  xN,  0, 0, 0);
      rR  = __builtin_amdgcn_mfma_f32_16x16x32_f16(wA1[0][ks], bh2[ks], rR,  0, 0, 0);
      rZ  = __builtin_amdgcn_mfma_f32_16x16x32_f16(wA1[1][ks], bh2[ks], rZ,  0, 0, 0);
      rNh = __builtin_amdgcn_mfma_f32_16x16x32_f16(wA1[2][ks], bh2[ks], rNh, 0, 0, 0);
    }
    f32x4 tR, tZ;
    #pragma unroll
    for (int i = 0; i < 4; ++i) { tR[i] = xR[i] + rR[i]; tZ[i] = xZ[i] + rZ[i]; }
    float hnv1[4];
    gates(tR, tZ, xN, rNh, h_old1, hnv1);
    *(float4*)&h2out[(size_t)(r0 + lr) * H_DIM + j0] =
        make_float4(hnv1[0], hnv1[1], hnv1[2], hnv1[3]);
  }
}

// FC head: out = fc2( BN( relu( fc1(h2_last) ) ) ); one row per block.
__global__ __launch_bounds__(64)
void head_kernel(const float* __restrict__ h2,
                 const float* __restrict__ fc1_w, const float* __restrict__ fc1_b,
                 const float* __restrict__ fc2_w, const float* __restrict__ fc2_b,
                 const float* __restrict__ gamma, const float* __restrict__ beta,
                 const float* __restrict__ mean,  const float* __restrict__ var,
                 float* __restrict__ out)
{
  const int row = blockIdx.x;
  const int j   = threadIdx.x;
  __shared__ __align__(16) float hrow[H_DIM];
  __shared__ __align__(16) float act[64];

  hrow[j]      = h2[(size_t)row * H_DIM + j];
  hrow[64 + j] = h2[(size_t)row * H_DIM + 64 + j];
  __syncthreads();

  float s = fc1_b[j];
  const float4* wr = reinterpret_cast<const float4*>(fc1_w + (size_t)j * H_DIM);
  #pragma unroll
  for (int k4 = 0; k4 < H_DIM / 4; ++k4) {
    const float4 w = wr[k4];
    const float4 h = reinterpret_cast<const float4*>(hrow)[k4];
    s += w.x * h.x + w.y * h.y + w.z * h.z + w.w * h.w;
  }
  s = fmaxf(s, 0.f);
  s = (s - mean[j]) * rsqrtf(var[j] + 1e-5f) * gamma[j] + beta[j];
  act[j] = s;
  __syncthreads();

  if (j < 2) {
    float o = fc2_b[j];
    #pragma unroll
    for (int k = 0; k < 64; ++k) o += fc2_w[(size_t)j * 64 + k] * act[k];
    out[(size_t)row * 2 + j] = o;
  }
}

} // namespace

extern "C" void kernel_launch(void* const* d_in, const int* in_sizes, int n_in,
                              void* d_out, int out_size, void* d_ws, size_t ws_size,
                              hipStream_t stream) {
  const float* x     = (const float*)d_in[0];
  const float* w_ih0 = (const float*)d_in[1];
  const float* w_hh0 = (const float*)d_in[2];
  const float* b_ih0 = (const float*)d_in[3];
  const float* b_hh0 = (const float*)d_in[4];
  const float* w_ih1 = (const float*)d_in[5];
  const float* w_hh1 = (const float*)d_in[6];
  const float* b_ih1 = (const float*)d_in[7];
  const float* b_hh1 = (const float*)d_in[8];
  const float* fc1_w = (const float*)d_in[9];
  const float* fc1_b = (const float*)d_in[10];
  const float* fc2_w = (const float*)d_in[11];
  const float* fc2_b = (const float*)d_in[12];
  const float* gamma = (const float*)d_in[13];
  const float* beta  = (const float*)d_in[14];
  const float* mean  = (const float*)d_in[15];
  const float* var   = (const float*)d_in[16];
  float* out = (float*)d_out;

  const size_t h2_bytes = (size_t)B_SZ * H_DIM * sizeof(float);  // 512 KB
  if (ws_size < h2_bytes) return;  // fail visibly
  float* h2 = (float*)d_ws;

  gru2<<<dim3(B_SZ / ROWS), dim3(NT), 0, stream>>>(
      x, w_ih0, w_hh0, b_ih0, b_hh0, w_ih1, w_hh1, b_ih1, b_hh1, h2);
  head_kernel<<<dim3(B_SZ), dim3(64), 0, stream>>>(
      h2, fc1_w, fc1_b, fc2_w, fc2_b, gamma, beta, mean, var, out);
}

// Round 12
// 658.788 us; speedup vs baseline: 2.0284x; 2.0284x over previous
//
#include <hip/hip_runtime.h>
#include <hip/hip_bf16.h>

namespace {

typedef _Float16 h16;
typedef _Float16 f16x8 __attribute__((ext_vector_type(8)));
typedef _Float16 f16x4 __attribute__((ext_vector_type(4)));
typedef _Float16 f16x2 __attribute__((ext_vector_type(2)));
typedef float    f32x4 __attribute__((ext_vector_type(4)));
typedef unsigned long long u64;

constexpr int T_SEQ = 512;
constexpr int B_SZ  = 1024;
constexpr int H_DIM = 128;
constexpr int ROWS  = 16;           // batch rows per group (MFMA N-tile)
constexpr int NT    = 512;          // 8 waves
constexpr int NGRP  = B_SZ / ROWS;  // 64 groups -> 128 blocks
constexpr int CHUNK = 32;           // steps per producer->consumer handoff

// Producer block g: layer-0 for batch group g (r5 structure), publishes h1(t)
// via agent-scope relaxed atomics; every CHUNK steps: fence + release flag.
// Consumer block g: layer-1, gated per chunk (spin amortized 32x), 1-deep
// h1 prefetch. __launch_bounds__(NT,1) -> 1 block/CU -> 128 distinct CUs,
// no producer/consumer CU-sharing (r7's actual failure mode).
template <int INDIM, bool PROD>
__device__ void gru_body(char* smem_raw,
                         const float* __restrict__ xin,
                         const float* __restrict__ w_ih,
                         const float* __restrict__ w_hh,
                         const float* __restrict__ b_ih,
                         const float* __restrict__ b_hh,
                         u64* __restrict__ h1q,    // [T][B][32] u64
                         int* __restrict__ flag,   // this group's chunk count
                         float* __restrict__ h2out,
                         const int g)
{
  constexpr int KSH  = H_DIM / 32;
  constexpr int KSX  = INDIM / 32;
  constexpr int ROWP = H_DIM + INDIM + 8;   // r5-proven pad (16B-aligned rows)

  auto hx = reinterpret_cast<h16 (*)[ROWS][ROWP]>(smem_raw);

  const int tid = threadIdx.x;
  const int wv  = tid >> 6;
  const int ln  = tid & 63;
  const int q   = ln >> 4;
  const int lr  = ln & 15;
  const int r0  = g * ROWS;
  const int j0  = wv * 16 + q * 4;

  // ---- weights -> fp16 frags (rounds 4-8 verified layout) ----
  f16x8 wA[3][KSH], wB[3][KSX];
  #pragma unroll
  for (int p = 0; p < 3; ++p) {
    const int gr = p * H_DIM + wv * 16 + lr;
    #pragma unroll
    for (int ks = 0; ks < KSH; ++ks) {
      const float* pw = w_hh + (size_t)gr * H_DIM + ks * 32 + q * 8;
      const float4 v0 = *(const float4*)(pw);
      const float4 v1 = *(const float4*)(pw + 4);
      f16x8 f;
      f[0]=(h16)v0.x; f[1]=(h16)v0.y; f[2]=(h16)v0.z; f[3]=(h16)v0.w;
      f[4]=(h16)v1.x; f[5]=(h16)v1.y; f[6]=(h16)v1.z; f[7]=(h16)v1.w;
      wA[p][ks] = f;
    }
    #pragma unroll
    for (int ks = 0; ks < KSX; ++ks) {
      const float* pw = w_ih + (size_t)gr * INDIM + ks * 32 + q * 8;
      const float4 v0 = *(const float4*)(pw);
      const float4 v1 = *(const float4*)(pw + 4);
      f16x8 f;
      f[0]=(h16)v0.x; f[1]=(h16)v0.y; f[2]=(h16)v0.z; f[3]=(h16)v0.w;
      f[4]=(h16)v1.x; f[5]=(h16)v1.y; f[6]=(h16)v1.z; f[7]=(h16)v1.w;
      wB[p][ks] = f;
    }
  }

  // ---- biases folded into MFMA C-init ----
  f32x4 bR, bZ, bNx, bNh;
  {
    const float4 ir  = *(const float4*)&b_ih[j0];
    const float4 hr  = *(const float4*)&b_hh[j0];
    const float4 iz  = *(const float4*)&b_ih[H_DIM + j0];
    const float4 hz  = *(const float4*)&b_hh[H_DIM + j0];
    const float4 in_ = *(const float4*)&b_ih[2 * H_DIM + j0];
    const float4 hn  = *(const float4*)&b_hh[2 * H_DIM + j0];
    bR[0]=ir.x+hr.x; bR[1]=ir.y+hr.y; bR[2]=ir.z+hr.z; bR[3]=ir.w+hr.w;
    bZ[0]=iz.x+hz.x; bZ[1]=iz.y+hz.y; bZ[2]=iz.z+hz.z; bZ[3]=iz.w+hz.w;
    bNx[0]=in_.x; bNx[1]=in_.y; bNx[2]=in_.z; bNx[3]=in_.w;
    bNh[0]=hn.x;  bNh[1]=hn.y;  bNh[2]=hn.z;  bNh[3]=hn.w;
  }

  const int sr = tid >> 5;   // 0..15
  const int si = tid & 31;   // 0..31

  // ---- prologue: zero h-state in buf0 ----
  {
    f16x4 z; z[0]=z[1]=z[2]=z[3] = (h16)0.f;
    *(f16x4*)&hx[0][sr][si * 4] = z;
  }
  f16x4 h_old; h_old[0]=h_old[1]=h_old[2]=h_old[3] = (h16)0.f;

  f16x2 sA, sB;    // producer x-prefetch ping-pong
  if constexpr (PROD) {
    const float2 v0 = *(const float2*)(xin + ((size_t)(r0 + sr) * T_SEQ + 0) * 64 + si * 2);
    f16x2 s0; s0[0] = (h16)v0.x; s0[1] = (h16)v0.y;
    *(f16x2*)&hx[0][sr][H_DIM + si * 2] = s0;
    const float2 v1 = *(const float2*)(xin + ((size_t)(r0 + sr) * T_SEQ + 1) * 64 + si * 2);
    sA[0] = (h16)v1.x; sA[1] = (h16)v1.y;
  } else {
    while (__hip_atomic_load(flag, __ATOMIC_ACQUIRE, __HIP_MEMORY_SCOPE_AGENT) < 1)
      __builtin_amdgcn_s_sleep(2);
    const u64 bits = __hip_atomic_load(&h1q[((size_t)0 * B_SZ + r0 + sr) * 32 + si],
                                       __ATOMIC_RELAXED, __HIP_MEMORY_SCOPE_AGENT);
    f16x4 s0; __builtin_memcpy(&s0, &bits, 8);
    *(f16x4*)&hx[0][sr][H_DIM + si * 4] = s0;
  }
  __syncthreads();

  auto gates = [&](const f32x4& aR, const f32x4& aZ, const f32x4& aNx2, const f32x4& aNh2,
                   f16x4& nv4, float* hnv) {
    #pragma unroll
    for (int i = 0; i < 4; ++i) {
      const float rg = __builtin_amdgcn_rcpf(1.f + __expf(-aR[i]));
      const float zg = __builtin_amdgcn_rcpf(1.f + __expf(-aZ[i]));
      const float na = aNx2[i] + rg * aNh2[i];
      const float e2 = __expf(2.f * na);
      const float ng = 1.f - 2.f * __builtin_amdgcn_rcpf(e2 + 1.f);
      const float ho = (float)h_old[i];
      const float hn = ng + zg * (ho - ng);
      hnv[i] = hn;
      nv4[i] = (h16)hn;
    }
    h_old = nv4;
  };

  if constexpr (PROD) {
    auto pstep = [&](int t, int cur, f16x2& s_use, f16x2& s_load) {
      f16x8 bh[KSH], bx[KSX];
      #pragma unroll
      for (int ks = 0; ks < KSH; ++ks) bh[ks] = *(const f16x8*)&hx[cur][lr][ks * 32 + q * 8];
      #pragma unroll
      for (int ks = 0; ks < KSX; ++ks) bx[ks] = *(const f16x8*)&hx[cur][lr][H_DIM + ks * 32 + q * 8];

      {  // prefetch x(t+2), 2-deep
        const int tt = (t + 2 < T_SEQ) ? t + 2 : T_SEQ - 1;
        const float2 v = *(const float2*)(xin + ((size_t)(r0 + sr) * T_SEQ + tt) * 64 + si * 2);
        s_load[0] = (h16)v.x; s_load[1] = (h16)v.y;
      }

      f32x4 aR = bR, aZ = bZ, aNh2 = bNh, aNx2 = bNx;
      #pragma unroll
      for (int ks = 0; ks < KSH; ++ks) {
        aR   = __builtin_amdgcn_mfma_f32_16x16x32_f16(wA[0][ks], bh[ks], aR, 0, 0, 0);
        aZ   = __builtin_amdgcn_mfma_f32_16x16x32_f16(wA[1][ks], bh[ks], aZ, 0, 0, 0);
        aNh2 = __builtin_amdgcn_mfma_f32_16x16x32_f16(wA[2][ks], bh[ks], aNh2, 0, 0, 0);
      }
      #pragma unroll
      for (int ks = 0; ks < KSX; ++ks) {
        aR   = __builtin_amdgcn_mfma_f32_16x16x32_f16(wB[0][ks], bx[ks], aR, 0, 0, 0);
        aZ   = __builtin_amdgcn_mfma_f32_16x16x32_f16(wB[1][ks], bx[ks], aZ, 0, 0, 0);
        aNx2 = __builtin_amdgcn_mfma_f32_16x16x32_f16(wB[2][ks], bx[ks], aNx2, 0, 0, 0);
      }

      f16x4 nv4; float hnv[4];
      gates(aR, aZ, aNx2, aNh2, nv4, hnv);

      u64 bits; __builtin_memcpy(&bits, &nv4, 8);
      __hip_atomic_store(&h1q[((size_t)t * B_SZ + r0 + lr) * 32 + (j0 >> 2)], bits,
                         __ATOMIC_RELAXED, __HIP_MEMORY_SCOPE_AGENT);

      *(f16x4*)&hx[cur ^ 1][lr][j0] = nv4;
      *(f16x2*)&hx[cur ^ 1][sr][H_DIM + si * 2] = s_use;

      if ((t & (CHUNK - 1)) == CHUNK - 1) __threadfence();  // once per chunk
      __syncthreads();
      if (((t & (CHUNK - 1)) == CHUNK - 1) && tid == 0)
        __hip_atomic_store(flag, (t + 1) >> 5, __ATOMIC_RELEASE, __HIP_MEMORY_SCOPE_AGENT);
    };

    #pragma unroll 1
    for (int t = 0; t < T_SEQ; t += 2) {
      pstep(t,     0, sA, sB);
      pstep(t + 1, 1, sB, sA);
    }
  } else {
    #pragma unroll 1
    for (int t = 0; t < T_SEQ; ++t) {
      const int cur = t & 1;
      f16x8 bh[KSH], bx[KSX];
      #pragma unroll
      for (int ks = 0; ks < KSH; ++ks) bh[ks] = *(const f16x8*)&hx[cur][lr][ks * 32 + q * 8];
      #pragma unroll
      for (int ks = 0; ks < KSX; ++ks) bx[ks] = *(const f16x8*)&hx[cur][lr][H_DIM + ks * 32 + q * 8];

      // prefetch h1(t+1): chunk-gated spin (only at 32-step boundaries)
      f16x4 sN;
      const bool have = (t + 1 < T_SEQ);
      if (have) {
        if (((t + 1) & (CHUNK - 1)) == 0) {
          const int need = ((t + 1) >> 5) + 1;
          while (__hip_atomic_load(flag, __ATOMIC_ACQUIRE, __HIP_MEMORY_SCOPE_AGENT) < need)
            __builtin_amdgcn_s_sleep(2);
        }
        const u64 bits = __hip_atomic_load(&h1q[((size_t)(t + 1) * B_SZ + r0 + sr) * 32 + si],
                                           __ATOMIC_RELAXED, __HIP_MEMORY_SCOPE_AGENT);
        __builtin_memcpy(&sN, &bits, 8);
      }

      f32x4 aR = bR, aZ = bZ, aNh2 = bNh, aNx2 = bNx;
      #pragma unroll
      for (int ks = 0; ks < KSH; ++ks) {
        aR   = __builtin_amdgcn_mfma_f32_16x16x32_f16(wA[0][ks], bh[ks], aR, 0, 0, 0);
        aZ   = __builtin_amdgcn_mfma_f32_16x16x32_f16(wA[1][ks], bh[ks], aZ, 0, 0, 0);
        aNh2 = __builtin_amdgcn_mfma_f32_16x16x32_f16(wA[2][ks], bh[ks], aNh2, 0, 0, 0);
      }
      #pragma unroll
      for (int ks = 0; ks < KSX; ++ks) {
        aR   = __builtin_amdgcn_mfma_f32_16x16x32_f16(wB[0][ks], bx[ks], aR, 0, 0, 0);
        aZ   = __builtin_amdgcn_mfma_f32_16x16x32_f16(wB[1][ks], bx[ks], aZ, 0, 0, 0);
        aNx2 = __builtin_amdgcn_mfma_f32_16x16x32_f16(wB[2][ks], bx[ks], aNx2, 0, 0, 0);
      }

      f16x4 nv4; float hnv[4];
      gates(aR, aZ, aNx2, aNh2, nv4, hnv);

      *(f16x4*)&hx[cur ^ 1][lr][j0] = nv4;
      if (have) *(f16x4*)&hx[cur ^ 1][sr][H_DIM + si * 4] = sN;
      if (t == T_SEQ - 1)
        *(float4*)&h2out[(size_t)(r0 + lr) * H_DIM + j0] =
            make_float4(hnv[0], hnv[1], hnv[2], hnv[3]);
      __syncthreads();
    }
  }
}

__global__ __launch_bounds__(NT, 1)   // 1 block/CU: producers & consumers on distinct CUs
void gru_fused(const float* __restrict__ x,
               const float* __restrict__ w_ih0, const float* __restrict__ w_hh0,
               const float* __restrict__ b_ih0, const float* __restrict__ b_hh0,
               const float* __restrict__ w_ih1, const float* __restrict__ w_hh1,
               const float* __restrict__ b_ih1, const float* __restrict__ b_hh1,
               u64* __restrict__ h1q, int* __restrict__ flags, float* __restrict__ h2)
{
  __shared__ __align__(16) char smem[(size_t)2 * ROWS * (H_DIM + H_DIM + 8) * sizeof(h16)];
  const int bid = blockIdx.x;
  if (bid < NGRP)
    gru_body<64, true>(smem, x, w_ih0, w_hh0, b_ih0, b_hh0, h1q, &flags[bid], nullptr, bid);
  else
    gru_body<128, false>(smem, nullptr, w_ih1, w_hh1, b_ih1, b_hh1, h1q,
                         &flags[bid - NGRP], h2, bid - NGRP);
}

// FC head: out = fc2( BN( relu( fc1(h2_last) ) ) ); one row per block.
__global__ __launch_bounds__(64)
void head_kernel(const float* __restrict__ h2,
                 const float* __restrict__ fc1_w, const float* __restrict__ fc1_b,
                 const float* __restrict__ fc2_w, const float* __restrict__ fc2_b,
                 const float* __restrict__ gamma, const float* __restrict__ beta,
                 const float* __restrict__ mean,  const float* __restrict__ var,
                 float* __restrict__ out)
{
  const int row = blockIdx.x;
  const int j   = threadIdx.x;
  __shared__ __align__(16) float hrow[H_DIM];
  __shared__ __align__(16) float act[64];

  hrow[j]      = h2[(size_t)row * H_DIM + j];
  hrow[64 + j] = h2[(size_t)row * H_DIM + 64 + j];
  __syncthreads();

  float s = fc1_b[j];
  const float4* wr = reinterpret_cast<const float4*>(fc1_w + (size_t)j * H_DIM);
  #pragma unroll
  for (int k4 = 0; k4 < H_DIM / 4; ++k4) {
    const float4 w = wr[k4];
    const float4 h = reinterpret_cast<const float4*>(hrow)[k4];
    s += w.x * h.x + w.y * h.y + w.z * h.z + w.w * h.w;
  }
  s = fmaxf(s, 0.f);
  s = (s - mean[j]) * rsqrtf(var[j] + 1e-5f) * gamma[j] + beta[j];
  act[j] = s;
  __syncthreads();

  if (j < 2) {
    float o = fc2_b[j];
    #pragma unroll
    for (int k = 0; k < 64; ++k) o += fc2_w[(size_t)j * 64 + k] * act[k];
    out[(size_t)row * 2 + j] = o;
  }
}

} // namespace

extern "C" void kernel_launch(void* const* d_in, const int* in_sizes, int n_in,
                              void* d_out, int out_size, void* d_ws, size_t ws_size,
                              hipStream_t stream) {
  const float* x     = (const float*)d_in[0];
  const float* w_ih0 = (const float*)d_in[1];
  const float* w_hh0 = (const float*)d_in[2];
  const float* b_ih0 = (const float*)d_in[3];
  const float* b_hh0 = (const float*)d_in[4];
  const float* w_ih1 = (const float*)d_in[5];
  const float* w_hh1 = (const float*)d_in[6];
  const float* b_ih1 = (const float*)d_in[7];
  const float* b_hh1 = (const float*)d_in[8];
  const float* fc1_w = (const float*)d_in[9];
  const float* fc1_b = (const float*)d_in[10];
  const float* fc2_w = (const float*)d_in[11];
  const float* fc2_b = (const float*)d_in[12];
  const float* gamma = (const float*)d_in[13];
  const float* beta  = (const float*)d_in[14];
  const float* mean  = (const float*)d_in[15];
  const float* var   = (const float*)d_in[16];
  float* out = (float*)d_out;

  char* ws = (char*)d_ws;
  const size_t h2_bytes = (size_t)B_SZ * H_DIM * sizeof(float);            // 512 KB
  const size_t h1_bytes = (size_t)T_SEQ * B_SZ * H_DIM * sizeof(h16);      // 134 MB
  const size_t fl_bytes = (size_t)NGRP * sizeof(int);
  if (ws_size < h2_bytes + h1_bytes + fl_bytes) return;  // fail visibly

  float* h2    = (float*)ws;
  u64*   h1q   = (u64*)(ws + h2_bytes);
  int*   flags = (int*)(ws + h2_bytes + h1_bytes);

  hipMemsetAsync(flags, 0, fl_bytes, stream);   // flags start at 0 each replay
  gru_fused<<<dim3(2 * NGRP), dim3(NT), 0, stream>>>(
      x, w_ih0, w_hh0, b_ih0, b_hh0, w_ih1, w_hh1, b_ih1, b_hh1, h1q, flags, h2);
  head_kernel<<<dim3(B_SZ), dim3(64), 0, stream>>>(
      h2, fc1_w, fc1_b, fc2_w, fc2_b, gamma, beta, mean, var, out);
}